// Round 10
// baseline (408.963 us; speedup 1.0000x reference)
//
#include <hip/hip_runtime.h>
#include <hip/hip_fp16.h>
#include <math.h>

#define N_NODES 100000
#define HALF 50000
#define N_EDGES 3200000
#define IN_DIM 11
#define HID 32
#define HID2 16
#define SCHUNK 100352   // per-array stride in ws (multiple of 128)
#define BINSHIFT 8
#define BINSZ 256
#define NB 391          // ceil(100000/256)
#define CHUNK 8192      // edges per block in hist/scatter (391 blocks)

#define NTL(p) __builtin_nontemporal_load(p)

// ---------------- binned CSR build (exact counts: hist -> scan -> scatter -> fill) --------
__global__ __launch_bounds__(1024) void k_hist(const int* __restrict__ ei,
                                               int* __restrict__ bincnt) {
    __shared__ int h[NB];
    for (int i = threadIdx.x; i < NB; i += 1024) h[i] = 0;
    __syncthreads();
    int b0 = blockIdx.x * CHUNK;
    int e1 = b0 + CHUNK; if (e1 > N_EDGES) e1 = N_EDGES;
    for (int e = b0 + threadIdx.x; e < e1; e += 1024)
        atomicAdd(&h[ei[N_EDGES + e] >> BINSHIFT], 1);
    __syncthreads();
    for (int i = threadIdx.x; i < NB; i += 1024)
        if (h[i]) atomicAdd(&bincnt[i], h[i]);
}

__global__ void k_scan_bins(const int* __restrict__ bincnt, int* __restrict__ binstart,
                            int* __restrict__ bincur, int* __restrict__ rowstart) {
    __shared__ int tmp[512];
    int v = (threadIdx.x < NB) ? bincnt[threadIdx.x] : 0;
    tmp[threadIdx.x] = v;
    __syncthreads();
    for (int off = 1; off < 512; off <<= 1) {
        int t = (threadIdx.x >= (unsigned)off) ? tmp[threadIdx.x - off] : 0;
        __syncthreads();
        tmp[threadIdx.x] += t;
        __syncthreads();
    }
    if (threadIdx.x < NB) {
        int ex = tmp[threadIdx.x] - v;
        binstart[threadIdx.x] = ex;
        bincur[threadIdx.x] = ex;
    }
    if (threadIdx.x == 0) {
        binstart[NB] = N_EDGES;
        rowstart[N_NODES] = N_EDGES;  // sentinel: end of last row
    }
}

__global__ __launch_bounds__(1024) void k_binscatter(const int* __restrict__ ei,
                                                     int* __restrict__ bincur,
                                                     unsigned* __restrict__ binbuf) {
    __shared__ int h[NB];
    __shared__ int base[NB];
    for (int i = threadIdx.x; i < NB; i += 1024) h[i] = 0;
    __syncthreads();
    int b0 = blockIdx.x * CHUNK;
    int e1 = b0 + CHUNK; if (e1 > N_EDGES) e1 = N_EDGES;
    for (int e = b0 + threadIdx.x; e < e1; e += 1024)
        atomicAdd(&h[ei[N_EDGES + e] >> BINSHIFT], 1);
    __syncthreads();
    for (int i = threadIdx.x; i < NB; i += 1024) {
        int c = h[i];
        if (c) base[i] = atomicAdd(&bincur[i], c);
        h[i] = 0;
    }
    __syncthreads();
    for (int e = b0 + threadIdx.x; e < e1; e += 1024) {
        int d = ei[N_EDGES + e];
        int s = ei[e];
        int b = d >> BINSHIFT;
        int p = base[b] + atomicAdd(&h[b], 1);
        binbuf[p] = (unsigned)s | ((unsigned)(d & (BINSZ - 1)) << 17);  // s < 2^17
    }
}

// one block per bin: per-(node, src-half) count -> 512-bucket LDS scan ->
// rowstart/rowmid/dinv -> fill csr with row-grouped, half-segmented edges
__global__ __launch_bounds__(1024) void k_binfill(const unsigned* __restrict__ binbuf,
                                                  const int* __restrict__ binstart,
                                                  int* __restrict__ rowstart,
                                                  int* __restrict__ rowmid,
                                                  float* __restrict__ dinv,
                                                  int* __restrict__ csr_src) {
    int b = blockIdx.x;
    int tid = threadIdx.x;
    int ebeg = binstart[b];
    int eend = binstart[b + 1];
    __shared__ int cnt[512];
    __shared__ int rloc[512];
    __shared__ int cur[512];
    __shared__ int tmp[512];
    if (tid < 512) cnt[tid] = 0;
    __syncthreads();
    for (int e = ebeg + tid; e < eend; e += 1024) {
        unsigned v = binbuf[e];
        int s = (int)(v & 0x1FFFFu);
        int bkt = (int)((v >> 17) << 1) | (s >= HALF);
        atomicAdd(&cnt[bkt], 1);
    }
    __syncthreads();
    int c = (tid < 512) ? cnt[tid] : 0;
    if (tid < 512) tmp[tid] = c;
    __syncthreads();
    for (int off = 1; off < 512; off <<= 1) {
        int t = (tid < 512 && tid >= off) ? tmp[tid - off] : 0;
        __syncthreads();
        if (tid < 512) tmp[tid] += t;
        __syncthreads();
    }
    if (tid < 512) {
        rloc[tid] = tmp[tid] - c;  // exclusive within bin (bucket-major: node*2 + half)
        cur[tid] = 0;
    }
    __syncthreads();
    if (tid < 256) {
        int node = b * BINSZ + tid;
        if (node < N_NODES) {
            int cl = cnt[2 * tid], ch = cnt[2 * tid + 1];
            rowstart[node] = ebeg + rloc[2 * tid];
            rowmid[node]   = ebeg + rloc[2 * tid + 1];  // == rowstart + cl
            dinv[node] = rsqrtf((float)(cl + ch) + 1.0f);  // +1 self-loop
        }
    }
    for (int e = ebeg + tid; e < eend; e += 1024) {
        unsigned v = binbuf[e];
        int s = (int)(v & 0x1FFFFu);
        int bkt = (int)((v >> 17) << 1) | (s >= HALF);
        int p = ebeg + rloc[bkt] + atomicAdd(&cur[bkt], 1);
        csr_src[p] = s;
    }
}

// ---------------- dense transforms (write dinv-scaled fp16, interleaved [node*32+j]) ------
__global__ void k_xw1(const float* __restrict__ x, const float* __restrict__ W1,
                      const float* __restrict__ dinv, __half* __restrict__ xwh) {
    int t = blockIdx.x * blockDim.x + threadIdx.x;
    int node = t >> 5;
    int j = t & 31;
    __shared__ float sW[IN_DIM * HID];
    __shared__ float sx[8 * IN_DIM];
    for (int i = threadIdx.x; i < IN_DIM * HID; i += 256) sW[i] = W1[i];
    int base = blockIdx.x * 8;  // 8 nodes per block
    if (threadIdx.x < 8 * IN_DIM) sx[threadIdx.x] = x[base * IN_DIM + threadIdx.x];
    __syncthreads();
    int ln = node - base;
    float acc = 0.0f;
#pragma unroll
    for (int k = 0; k < IN_DIM; ++k)
        acc += sx[ln * IN_DIM + k] * sW[k * HID + j];
    xwh[t] = __float2half(dinv[node] * acc);
}

__global__ void k_xw2(const float* __restrict__ h, const float* __restrict__ W2,
                      const float* __restrict__ dinv, __half* __restrict__ xwh) {
    int t = blockIdx.x * blockDim.x + threadIdx.x;
    int node = t >> 5;
    int j = t & 31;
    __shared__ float sW[HID * HID];
    for (int i = threadIdx.x; i < HID * HID; i += 256) sW[i] = W2[i];
    __syncthreads();
    float acc = 0.0f;
#pragma unroll
    for (int k = 0; k < HID; ++k)
        acc += h[node * HID + k] * sW[k * HID + j];
    xwh[t] = __float2half(dinv[node] * acc);
}

// ---------------- split CSR gather, pass A = src<HALF (3.2 MB L2-resident window) ---------
// All streaming traffic (csr, staged H) is non-temporal so L2 keeps only the XWH window.
__global__ __launch_bounds__(256) void k_gatherA(const int* __restrict__ rowstart,
                                                 const int* __restrict__ rowmid,
                                                 const int* __restrict__ csr_src,
                                                 const __half* __restrict__ xwh,
                                                 float* __restrict__ outb) {
    int node = blockIdx.x * 8 + (threadIdx.x >> 5);
    int j = threadIdx.x & 31;
    if (node >= N_NODES) return;
    int beg = rowstart[node];
    int end = rowmid[node];
    float acc = (node < HALF) ? __half2float(xwh[node * HID + j]) : 0.0f;  // self term
    int e = beg;
    for (; e + 8 <= end; e += 8) {
        int s0 = NTL(csr_src + e),     s1 = NTL(csr_src + e + 1);
        int s2 = NTL(csr_src + e + 2), s3 = NTL(csr_src + e + 3);
        int s4 = NTL(csr_src + e + 4), s5 = NTL(csr_src + e + 5);
        int s6 = NTL(csr_src + e + 6), s7 = NTL(csr_src + e + 7);
        float x0 = __half2float(xwh[s0 * HID + j]);
        float x1 = __half2float(xwh[s1 * HID + j]);
        float x2 = __half2float(xwh[s2 * HID + j]);
        float x3 = __half2float(xwh[s3 * HID + j]);
        float x4 = __half2float(xwh[s4 * HID + j]);
        float x5 = __half2float(xwh[s5 * HID + j]);
        float x6 = __half2float(xwh[s6 * HID + j]);
        float x7 = __half2float(xwh[s7 * HID + j]);
        acc += ((x0 + x1) + (x2 + x3)) + ((x4 + x5) + (x6 + x7));
    }
    for (; e < end; ++e)
        acc += __half2float(xwh[NTL(csr_src + e) * HID + j]);
    __builtin_nontemporal_store(acc, &outb[node * HID + j]);  // raw partial sum
}

// pass B = src>=HALF (other 3.2 MB window) + staged acc + dinv scale + bias/relu
__global__ __launch_bounds__(256) void k_gatherB(const int* __restrict__ rowmid,
                                                 const int* __restrict__ rowstart,
                                                 const float* __restrict__ dinv,
                                                 const int* __restrict__ csr_src,
                                                 const __half* __restrict__ xwh,
                                                 const float* __restrict__ bias,
                                                 float* __restrict__ outb, int do_relu) {
    int node = blockIdx.x * 8 + (threadIdx.x >> 5);
    int j = threadIdx.x & 31;
    if (node >= N_NODES) return;
    int beg = rowmid[node];
    int end = rowstart[node + 1];
    float acc = NTL(&outb[node * HID + j]) +
                ((node >= HALF) ? __half2float(xwh[node * HID + j]) : 0.0f);
    int e = beg;
    for (; e + 8 <= end; e += 8) {
        int s0 = NTL(csr_src + e),     s1 = NTL(csr_src + e + 1);
        int s2 = NTL(csr_src + e + 2), s3 = NTL(csr_src + e + 3);
        int s4 = NTL(csr_src + e + 4), s5 = NTL(csr_src + e + 5);
        int s6 = NTL(csr_src + e + 6), s7 = NTL(csr_src + e + 7);
        float x0 = __half2float(xwh[s0 * HID + j]);
        float x1 = __half2float(xwh[s1 * HID + j]);
        float x2 = __half2float(xwh[s2 * HID + j]);
        float x3 = __half2float(xwh[s3 * HID + j]);
        float x4 = __half2float(xwh[s4 * HID + j]);
        float x5 = __half2float(xwh[s5 * HID + j]);
        float x6 = __half2float(xwh[s6 * HID + j]);
        float x7 = __half2float(xwh[s7 * HID + j]);
        acc += ((x0 + x1) + (x2 + x3)) + ((x4 + x5) + (x6 + x7));
    }
    for (; e < end; ++e)
        acc += __half2float(xwh[NTL(csr_src + e) * HID + j]);
    float v = dinv[node] * acc;
    if (do_relu) {
        v += bias[j];
        v = v > 0.0f ? v : 0.0f;
    }
    __builtin_nontemporal_store(v, &outb[node * HID + j]);
}

// ---------------- output MLP ----------------
__global__ void k_mlp(const float* __restrict__ agg2, const float* __restrict__ b2,
                      const float* __restrict__ Wo1, const float* __restrict__ bo1,
                      const float* __restrict__ Wo2, const float* __restrict__ bo2,
                      float* __restrict__ out) {
    int node = blockIdx.x * blockDim.x + threadIdx.x;
    __shared__ float sW1[HID * HID2];
    __shared__ float sW2[HID2];
    __shared__ float sb1[HID2];
    for (int i = threadIdx.x; i < HID * HID2; i += blockDim.x) sW1[i] = Wo1[i];
    if (threadIdx.x < HID2) {
        sW2[threadIdx.x] = Wo2[threadIdx.x];
        sb1[threadIdx.x] = bo1[threadIdx.x];
    }
    __syncthreads();
    if (node >= N_NODES) return;
    float h[HID];
#pragma unroll
    for (int k = 0; k < HID; ++k) {
        float v = agg2[node * HID + k] + b2[k];
        h[k] = v > 0.0f ? v : 0.0f;
    }
    float o = bo2[0];
#pragma unroll
    for (int j = 0; j < HID2; ++j) {
        float a = sb1[j];
#pragma unroll
        for (int k = 0; k < HID; ++k) a += h[k] * sW1[k * HID2 + j];
        a = a > 0.0f ? a : (expf(a) - 1.0f);  // elu alpha=1
        o += a * sW2[j];
    }
    out[node] = o;
}

extern "C" void kernel_launch(void* const* d_in, const int* in_sizes, int n_in,
                              void* d_out, int out_size, void* d_ws, size_t ws_size,
                              hipStream_t stream) {
    const float* x   = (const float*)d_in[0];
    const int*   ei  = (const int*)d_in[1];
    const float* W1  = (const float*)d_in[3];
    const float* b1  = (const float*)d_in[4];
    const float* W2  = (const float*)d_in[5];
    const float* b2  = (const float*)d_in[6];
    const float* Wo1 = (const float*)d_in[7];
    const float* bo1 = (const float*)d_in[8];
    const float* Wo2 = (const float*)d_in[9];
    const float* bo2 = (const float*)d_in[10];
    float* out = (float*)d_out;

    // ws layout (4B units):
    // bincnt[512] | binstart[512] | bincur[512] | rowstart[SCHUNK] | rowmid[SCHUNK]
    // | dinv[SCHUNK] | csr_src[E] | H[N*HID fp32] | XWH[N*HID fp16]
    // binbuf (E u32) aliases H (dead during CSR build)
    int*   bincnt   = (int*)d_ws;
    int*   binstart = bincnt + 512;
    int*   bincur   = binstart + 512;
    int*   rowstart = bincur + 512;
    int*   rowmid   = rowstart + SCHUNK;
    float* dinv     = (float*)(rowmid + SCHUNK);
    int*   csr_src  = (int*)(dinv + SCHUNK);
    float* H        = (float*)(csr_src + N_EDGES);
    __half* XWH     = (__half*)(H + (size_t)N_NODES * HID);
    unsigned* binbuf = (unsigned*)H;

    const int BT = 256;
    int gN   = (N_NODES + BT - 1) / BT;             // 391
    int gNH  = (N_NODES * HID + BT - 1) / BT;       // 12500
    int gC   = (N_EDGES + CHUNK - 1) / CHUNK;       // 391
    int gG   = (N_NODES + 7) / 8;                   // 12500

    // binned CSR build (rowstart, rowmid, dinv, csr_src)
    hipMemsetAsync(bincnt, 0, NB * sizeof(int), stream);
    k_hist      <<<gC, 1024, 0, stream>>>(ei, bincnt);
    k_scan_bins <<<1, 512, 0, stream>>>(bincnt, binstart, bincur, rowstart);
    k_binscatter<<<gC, 1024, 0, stream>>>(ei, bincur, binbuf);
    k_binfill   <<<NB, 1024, 0, stream>>>(binbuf, binstart, rowstart, rowmid, dinv, csr_src);

    // layer 1
    k_xw1<<<gNH, BT, 0, stream>>>(x, W1, dinv, XWH);
    k_gatherA<<<gG, BT, 0, stream>>>(rowstart, rowmid, csr_src, XWH, H);
    k_gatherB<<<gG, BT, 0, stream>>>(rowmid, rowstart, dinv, csr_src, XWH, b1, H, 1);

    // layer 2 (bias+relu fused into mlp)
    k_xw2<<<gNH, BT, 0, stream>>>(H, W2, dinv, XWH);
    k_gatherA<<<gG, BT, 0, stream>>>(rowstart, rowmid, csr_src, XWH, H);
    k_gatherB<<<gG, BT, 0, stream>>>(rowmid, rowstart, dinv, csr_src, XWH, b1, H, 0);

    // head
    k_mlp<<<gN, BT, 0, stream>>>(H, b2, Wo1, bo1, Wo2, bo2, out);
}

// Round 11
// 291.500 us; speedup vs baseline: 1.4030x; 1.4030x over previous
//
#include <hip/hip_runtime.h>
#include <hip/hip_fp16.h>
#include <math.h>

#define N_NODES 100000
#define N_EDGES 3200000
#define IN_DIM 11
#define HID 32
#define HID2 16
#define SCHUNK 100352   // per-array stride in ws (multiple of 128)
#define BINSHIFT 8
#define BINSZ 256
#define NB 391          // ceil(100000/256)
#define CHUNK 8192      // edges per block in hist/scatter (391 blocks)

// ---------------- binned CSR build (exact counts; prefix computed in-block) ----------------
__global__ __launch_bounds__(1024) void k_hist(const int* __restrict__ ei,
                                               int* __restrict__ bincnt) {
    __shared__ int h[NB];
    for (int i = threadIdx.x; i < NB; i += 1024) h[i] = 0;
    __syncthreads();
    int b0 = blockIdx.x * CHUNK;
    int e1 = b0 + CHUNK; if (e1 > N_EDGES) e1 = N_EDGES;
    for (int e = b0 + threadIdx.x; e < e1; e += 1024)
        atomicAdd(&h[ei[N_EDGES + e] >> BINSHIFT], 1);
    __syncthreads();
    for (int i = threadIdx.x; i < NB; i += 1024)
        if (h[i]) atomicAdd(&bincnt[i], h[i]);
}

// chunked scatter into bin-contiguous binbuf; prefix over bincnt computed in-block;
// one global reservation atomic per (block,bin)
__global__ __launch_bounds__(1024) void k_binscatter(const int* __restrict__ ei,
                                                     const int* __restrict__ bincnt,
                                                     int* __restrict__ bincur,
                                                     unsigned* __restrict__ binbuf) {
    __shared__ int pre[NB];
    __shared__ int h[NB];
    __shared__ int base[NB];
    __shared__ int tmp[512];
    int tid = threadIdx.x;
    // exclusive prefix of bincnt (NB < 512)
    int v = (tid < NB) ? bincnt[tid] : 0;
    if (tid < 512) tmp[tid] = v;
    __syncthreads();
    for (int off = 1; off < 512; off <<= 1) {
        int t = (tid < 512 && tid >= off) ? tmp[tid - off] : 0;
        __syncthreads();
        if (tid < 512) tmp[tid] += t;
        __syncthreads();
    }
    if (tid < NB) pre[tid] = tmp[tid] - v;
    for (int i = tid; i < NB; i += 1024) h[i] = 0;
    __syncthreads();
    int b0 = blockIdx.x * CHUNK;
    int e1 = b0 + CHUNK; if (e1 > N_EDGES) e1 = N_EDGES;
    for (int e = b0 + tid; e < e1; e += 1024)
        atomicAdd(&h[ei[N_EDGES + e] >> BINSHIFT], 1);
    __syncthreads();
    for (int i = tid; i < NB; i += 1024) {
        int c = h[i];
        if (c) base[i] = pre[i] + atomicAdd(&bincur[i], c);
        h[i] = 0;
    }
    __syncthreads();
    for (int e = b0 + tid; e < e1; e += 1024) {
        int d = ei[N_EDGES + e];
        int s = ei[e];
        int b = d >> BINSHIFT;
        int p = base[b] + atomicAdd(&h[b], 1);
        binbuf[p] = (unsigned)s | ((unsigned)(d & (BINSZ - 1)) << 17);  // s < 2^17
    }
}

// one block (1024 thr) per bin: in-block prefix -> per-node count -> LDS scan ->
// rowstart/dinv -> fill csr row-grouped
__global__ __launch_bounds__(1024) void k_binfill(const unsigned* __restrict__ binbuf,
                                                  const int* __restrict__ bincnt,
                                                  int* __restrict__ rowstart,
                                                  float* __restrict__ dinv,
                                                  int* __restrict__ csr_src) {
    int b = blockIdx.x;
    int tid = threadIdx.x;
    __shared__ int tmp[512];
    __shared__ int cnt[BINSZ];
    __shared__ int rloc[BINSZ];
    __shared__ int cur[BINSZ];
    // ebeg = sum of bincnt[0..b)
    int v = (tid < 512 && tid < b) ? bincnt[tid] : 0;
    if (tid < 512) tmp[tid] = v;
    __syncthreads();
    for (int off = 256; off >= 1; off >>= 1) {
        if (tid < off) tmp[tid] += tmp[tid + off];
        __syncthreads();
    }
    int ebeg = tmp[0];
    int eend = ebeg + bincnt[b];
    __syncthreads();  // tmp reused below
    if (tid < BINSZ) cnt[tid] = 0;
    __syncthreads();
    for (int e = ebeg + tid; e < eend; e += 1024)
        atomicAdd(&cnt[binbuf[e] >> 17], 1);
    __syncthreads();
    int c = (tid < BINSZ) ? cnt[tid] : 0;
    if (tid < BINSZ) tmp[tid] = c;
    __syncthreads();
    for (int off = 1; off < BINSZ; off <<= 1) {
        int t = (tid < BINSZ && tid >= off) ? tmp[tid - off] : 0;
        __syncthreads();
        if (tid < BINSZ) tmp[tid] += t;
        __syncthreads();
    }
    if (tid < BINSZ) {
        rloc[tid] = tmp[tid] - c;  // exclusive within bin
        cur[tid] = 0;
        int node = b * BINSZ + tid;
        if (node < N_NODES) {
            rowstart[node] = ebeg + rloc[tid];
            dinv[node] = rsqrtf((float)c + 1.0f);  // +1 self-loop
        }
    }
    if (b == 0 && tid == 0) rowstart[N_NODES] = N_EDGES;  // sentinel
    __syncthreads();
    for (int e = ebeg + tid; e < eend; e += 1024) {
        unsigned vv = binbuf[e];
        int dl = vv >> 17;
        int s = (int)(vv & 0x1FFFFu);
        int p = ebeg + rloc[dl] + atomicAdd(&cur[dl], 1);
        csr_src[p] = s;
    }
}

// ---------------- dense transforms (write dinv-scaled fp16, interleaved [node*32+j]) ------
__global__ void k_xw1(const float* __restrict__ x, const float* __restrict__ W1,
                      const float* __restrict__ dinv, __half* __restrict__ xwh) {
    int t = blockIdx.x * blockDim.x + threadIdx.x;
    int node = t >> 5;
    int j = t & 31;
    __shared__ float sW[IN_DIM * HID];
    __shared__ float sx[8 * IN_DIM];
    for (int i = threadIdx.x; i < IN_DIM * HID; i += 256) sW[i] = W1[i];
    int base = blockIdx.x * 8;  // 8 nodes per block
    if (threadIdx.x < 8 * IN_DIM) sx[threadIdx.x] = x[base * IN_DIM + threadIdx.x];
    __syncthreads();
    int ln = node - base;
    float acc = 0.0f;
#pragma unroll
    for (int k = 0; k < IN_DIM; ++k)
        acc += sx[ln * IN_DIM + k] * sW[k * HID + j];
    xwh[t] = __float2half(dinv[node] * acc);
}

__global__ void k_xw2(const float* __restrict__ h, const float* __restrict__ W2,
                      const float* __restrict__ dinv, __half* __restrict__ xwh) {
    int t = blockIdx.x * blockDim.x + threadIdx.x;
    int node = t >> 5;
    int j = t & 31;
    __shared__ float sW[HID * HID];
    for (int i = threadIdx.x; i < HID * HID; i += 256) sW[i] = W2[i];
    __syncthreads();
    float acc = 0.0f;
#pragma unroll
    for (int k = 0; k < HID; ++k)
        acc += h[node * HID + k] * sW[k * HID + j];
    xwh[t] = __float2half(dinv[node] * acc);
}

// ---------------- monolithic CSR gather (layer 1: + bias + relu -> H) ----------------
__global__ __launch_bounds__(256) void k_gather(const int* __restrict__ rowstart,
                                                const float* __restrict__ dinv,
                                                const int* __restrict__ csr_src,
                                                const __half* __restrict__ xwh,
                                                const float* __restrict__ bias,
                                                float* __restrict__ outb) {
    int node = blockIdx.x * 8 + (threadIdx.x >> 5);
    int j = threadIdx.x & 31;
    int beg = rowstart[node];
    int end = rowstart[node + 1];
    float acc = 0.0f;
    int e = beg;
    for (; e + 8 <= end; e += 8) {
        int s0 = csr_src[e],     s1 = csr_src[e + 1], s2 = csr_src[e + 2], s3 = csr_src[e + 3];
        int s4 = csr_src[e + 4], s5 = csr_src[e + 5], s6 = csr_src[e + 6], s7 = csr_src[e + 7];
        float x0 = __half2float(xwh[s0 * HID + j]);
        float x1 = __half2float(xwh[s1 * HID + j]);
        float x2 = __half2float(xwh[s2 * HID + j]);
        float x3 = __half2float(xwh[s3 * HID + j]);
        float x4 = __half2float(xwh[s4 * HID + j]);
        float x5 = __half2float(xwh[s5 * HID + j]);
        float x6 = __half2float(xwh[s6 * HID + j]);
        float x7 = __half2float(xwh[s7 * HID + j]);
        acc += ((x0 + x1) + (x2 + x3)) + ((x4 + x5) + (x6 + x7));
    }
    for (; e + 2 <= end; e += 2) {
        int s0 = csr_src[e], s1 = csr_src[e + 1];
        acc += __half2float(xwh[s0 * HID + j]) + __half2float(xwh[s1 * HID + j]);
    }
    for (; e < end; ++e)
        acc += __half2float(xwh[csr_src[e] * HID + j]);
    float dd = dinv[node];
    float v = dd * (acc + __half2float(xwh[node * HID + j])) + bias[j];
    outb[node * HID + j] = v > 0.0f ? v : 0.0f;
}

// ---------------- layer-2 gather fused with bias2+relu and the output MLP ----------------
// grid is exactly N_NODES/8 blocks -> no early returns -> __syncthreads is safe
__global__ __launch_bounds__(256) void k_gather_mlp(const int* __restrict__ rowstart,
                                                    const float* __restrict__ dinv,
                                                    const int* __restrict__ csr_src,
                                                    const __half* __restrict__ xwh,
                                                    const float* __restrict__ b2,
                                                    const float* __restrict__ Wo1,
                                                    const float* __restrict__ bo1,
                                                    const float* __restrict__ Wo2,
                                                    const float* __restrict__ bo2,
                                                    float* __restrict__ out) {
    __shared__ float sW1[HID * HID2];
    __shared__ float sb1[HID2];
    __shared__ float sW2[HID2];
    __shared__ float sb2[HID];
    __shared__ float sH[8 * 33];  // 8 nodes x 32 feats, stride 33 vs bank conflicts
    for (int i = threadIdx.x; i < HID * HID2; i += 256) sW1[i] = Wo1[i];
    if (threadIdx.x < HID2) {
        sb1[threadIdx.x] = bo1[threadIdx.x];
        sW2[threadIdx.x] = Wo2[threadIdx.x];
    }
    if (threadIdx.x < HID) sb2[threadIdx.x] = b2[threadIdx.x];

    int ln = threadIdx.x >> 5;             // node-in-block
    int node = blockIdx.x * 8 + ln;
    int j = threadIdx.x & 31;
    int beg = rowstart[node];
    int end = rowstart[node + 1];
    float acc = 0.0f;
    int e = beg;
    for (; e + 8 <= end; e += 8) {
        int s0 = csr_src[e],     s1 = csr_src[e + 1], s2 = csr_src[e + 2], s3 = csr_src[e + 3];
        int s4 = csr_src[e + 4], s5 = csr_src[e + 5], s6 = csr_src[e + 6], s7 = csr_src[e + 7];
        float x0 = __half2float(xwh[s0 * HID + j]);
        float x1 = __half2float(xwh[s1 * HID + j]);
        float x2 = __half2float(xwh[s2 * HID + j]);
        float x3 = __half2float(xwh[s3 * HID + j]);
        float x4 = __half2float(xwh[s4 * HID + j]);
        float x5 = __half2float(xwh[s5 * HID + j]);
        float x6 = __half2float(xwh[s6 * HID + j]);
        float x7 = __half2float(xwh[s7 * HID + j]);
        acc += ((x0 + x1) + (x2 + x3)) + ((x4 + x5) + (x6 + x7));
    }
    for (; e + 2 <= end; e += 2) {
        int s0 = csr_src[e], s1 = csr_src[e + 1];
        acc += __half2float(xwh[s0 * HID + j]) + __half2float(xwh[s1 * HID + j]);
    }
    for (; e < end; ++e)
        acc += __half2float(xwh[csr_src[e] * HID + j]);
    float dd = dinv[node];
    float hv = dd * (acc + __half2float(xwh[node * HID + j])) + sb2[j];
    sH[ln * 33 + j] = hv > 0.0f ? hv : 0.0f;  // relu(agg + b2)
    __syncthreads();  // also covers the weight staging above

    // MLP: lanes 0..15 compute the 16 hidden units; shuffle-reduce 16->1
    float val = 0.0f;
    if (j < HID2) {
        float a = sb1[j];
#pragma unroll
        for (int k = 0; k < HID; ++k) a += sH[ln * 33 + k] * sW1[k * HID2 + j];
        a = a > 0.0f ? a : (expf(a) - 1.0f);  // elu alpha=1
        val = a * sW2[j];
    }
#pragma unroll
    for (int d = 16; d >= 1; d >>= 1) val += __shfl_down(val, d, 32);
    if (j == 0) out[node] = val + bo2[0];
}

extern "C" void kernel_launch(void* const* d_in, const int* in_sizes, int n_in,
                              void* d_out, int out_size, void* d_ws, size_t ws_size,
                              hipStream_t stream) {
    const float* x   = (const float*)d_in[0];
    const int*   ei  = (const int*)d_in[1];
    const float* W1  = (const float*)d_in[3];
    const float* b1  = (const float*)d_in[4];
    const float* W2  = (const float*)d_in[5];
    const float* b2  = (const float*)d_in[6];
    const float* Wo1 = (const float*)d_in[7];
    const float* bo1 = (const float*)d_in[8];
    const float* Wo2 = (const float*)d_in[9];
    const float* bo2 = (const float*)d_in[10];
    float* out = (float*)d_out;

    // ws layout (4B units):
    // bincnt[512] | bincur[512] | rowstart[SCHUNK] | dinv[SCHUNK]
    // | csr_src[E] | H[N*HID fp32] | XWH[N*HID fp16]
    // binbuf (E u32) aliases H (dead during CSR build)
    int*   bincnt   = (int*)d_ws;
    int*   bincur   = bincnt + 512;
    int*   rowstart = bincur + 512;
    float* dinv     = (float*)(rowstart + SCHUNK);
    int*   csr_src  = (int*)(dinv + SCHUNK);
    float* H        = (float*)(csr_src + N_EDGES);
    __half* XWH     = (__half*)(H + (size_t)N_NODES * HID);
    unsigned* binbuf = (unsigned*)H;

    const int BT = 256;
    int gNH  = (N_NODES * HID + BT - 1) / BT;       // 12500
    int gC   = (N_EDGES + CHUNK - 1) / CHUNK;       // 391
    int gG   = N_NODES / 8;                         // 12500 (exact)

    // binned CSR build (rowstart, dinv, csr_src)
    hipMemsetAsync(bincnt, 0, 1024 * sizeof(int), stream);  // bincnt + bincur
    k_hist      <<<gC, 1024, 0, stream>>>(ei, bincnt);
    k_binscatter<<<gC, 1024, 0, stream>>>(ei, bincnt, bincur, binbuf);
    k_binfill   <<<NB, 1024, 0, stream>>>(binbuf, bincnt, rowstart, dinv, csr_src);

    // layer 1: XWH = fp16(dinv .* (x@W1)) ; H = relu(dinv.*gather(XWH) + b1)
    k_xw1<<<gNH, BT, 0, stream>>>(x, W1, dinv, XWH);
    k_gather<<<gG, BT, 0, stream>>>(rowstart, dinv, csr_src, XWH, b1, H);

    // layer 2: XWH = fp16(dinv .* (H@W2)) ; out = MLP(relu(dinv.*gather(XWH) + b2))
    k_xw2<<<gNH, BT, 0, stream>>>(H, W2, dinv, XWH);
    k_gather_mlp<<<gG, BT, 0, stream>>>(rowstart, dinv, csr_src, XWH,
                                        b2, Wo1, bo1, Wo2, bo2, out);
}